// Round 9
// baseline (236.916 us; speedup 1.0000x reference)
//
#include <hip/hip_runtime.h>
#include <hip/hip_bf16.h>
#include <math.h>

// Problem constants (GPT-2 small causal self-attention)
constexpr int Bz = 8;      // batch
constexpr int Tt = 1024;   // seq len
constexpr int Cc = 768;    // n_embd
constexpr int Hh = 12;     // heads
constexpr int Dd = 64;     // head dim
constexpr int BT = Bz * Tt;        // 8192 rows
constexpr int C3 = 3 * Cc;         // 2304

using bf16x8 = __attribute__((ext_vector_type(8))) short;
using bf16x4 = __attribute__((ext_vector_type(4))) short;
using u16x8  = __attribute__((ext_vector_type(8))) unsigned short;
using f32x4  = __attribute__((ext_vector_type(4))) float;

__device__ __forceinline__ unsigned short f2bf(float f) {   // bit-exact RNE (cold paths)
  unsigned int u = __builtin_bit_cast(unsigned int, f);
  u += 0x7fffu + ((u >> 16) & 1u);
  return (unsigned short)(u >> 16);
}
__device__ __forceinline__ short f2bf_hw(float f) {         // HW cvt (hot path)
  __hip_bfloat16 h = __float2bfloat16(f);
  return __builtin_bit_cast(short, h);
}
__device__ __forceinline__ float fast_exp2(float x) {
#if __has_builtin(__builtin_amdgcn_exp2f)
  return __builtin_amdgcn_exp2f(x);
#else
  return exp2f(x);
#endif
}
__device__ __forceinline__ f32x4 mfma16_bf16(bf16x4 a, bf16x4 b, f32x4 c) {
#if __has_builtin(__builtin_amdgcn_mfma_f32_16x16x16bf16_1k)
  return __builtin_amdgcn_mfma_f32_16x16x16bf16_1k(a, b, c, 0, 0, 0);
#else
  asm volatile("v_mfma_f32_16x16x16_bf16 %0, %1, %2, %0" : "+v"(c) : "v"(a), "v"(b));
  return c;
#endif
}
// async global->LDS, 16B per lane; dest is wave-uniform base + lane*16 (m97/m104)
__device__ __forceinline__ void stage16(const unsigned short* g, unsigned short* l) {
  __builtin_amdgcn_global_load_lds(
      (const __attribute__((address_space(1))) void*)g,
      (__attribute__((address_space(3))) void*)l, 16, 0, 0);
}

// ---------------------------------------------------------------------------
// x fp32 -> bf16, vectorized. 8 elems/thread.
// ---------------------------------------------------------------------------
__global__ __launch_bounds__(256) void xcast_kernel(
    const float* __restrict__ in, unsigned short* __restrict__ out) {
  const size_t i = ((size_t)blockIdx.x * 256 + threadIdx.x) * 8;
  const float4 a = *(const float4*)(in + i);
  const float4 b = *(const float4*)(in + i + 4);
  u16x8 w;
  w[0] = f2bf(a.x); w[1] = f2bf(a.y); w[2] = f2bf(a.z); w[3] = f2bf(a.w);
  w[4] = f2bf(b.x); w[5] = f2bf(b.y); w[6] = f2bf(b.z); w[7] = f2bf(b.w);
  *(u16x8*)(out + i) = w;
}

// ---------------------------------------------------------------------------
// Transpose + cast: in[K][N] fp32 -> out[N][K] bf16.  block(32,8), grid(N/32,K/32)
// ---------------------------------------------------------------------------
__global__ __launch_bounds__(256) void tcast_kernel(
    const float* __restrict__ in, unsigned short* __restrict__ out, int K, int N) {
  __shared__ float t[32][33];
  const int tx = threadIdx.x, ty = threadIdx.y;
  const int kb = blockIdx.y * 32, nb = blockIdx.x * 32;
#pragma unroll
  for (int i = 0; i < 4; ++i)
    t[ty + 8 * i][tx] = in[(size_t)(kb + ty + 8 * i) * N + nb + tx];
  __syncthreads();
#pragma unroll
  for (int i = 0; i < 4; ++i)
    out[(size_t)(nb + ty + 8 * i) * K + kb + tx] = f2bf(t[tx][ty + 8 * i]);
}

// ---------------------------------------------------------------------------
// m97-structure MFMA GEMM core (B^T input, both bf16):
// 128x128 tile, BK=32, linear LDS [128][32], global_load_lds width 16.
// Wave w stages A/B chunks (w*2, w*2+1); chunk = 16 rows = 1KB.
// Verified mapping: lane l writes LDS byte c*1024 + 64*(l>>2) + 16*(l&3)
// == As[16c + (l>>2)][(l&3)*8], matching its global source row/col.
// ---------------------------------------------------------------------------
#define GEMM_CORE_PROLOGUE()                                                   \
  __shared__ unsigned short As[128 * 32];                                      \
  __shared__ unsigned short Bs[128 * 32];                                      \
  const int tid = threadIdx.x;                                                 \
  const int wave = tid >> 6, lane = tid & 63;                                  \
  const int wr = wave >> 1, wc = wave & 1;                                     \
  const int lr = lane & 15;                                                    \
  const int lg = lane >> 4;                                                    \
  const int lrow = lane >> 2;                                                  \
  const int lcol = (lane & 3) * 8;                                             \
  const int brow = blockIdx.y * 128, bcol = blockIdx.x * 128;                  \
  f32x4 acc[4][4] = {};                                                        \
  for (int kt = 0; kt < K / 32; ++kt) {                                        \
    const int k0 = kt * 32;                                                    \
    __syncthreads();                                                           \
    _Pragma("unroll")                                                          \
    for (int i = 0; i < 2; ++i) {                                              \
      const int chunk = wave * 2 + i;                                          \
      const int row = chunk * 16 + lrow;                                       \
      stage16(A + (size_t)(brow + row) * K + k0 + lcol, &As[chunk * 512]);     \
      stage16(Bt + (size_t)(bcol + row) * K + k0 + lcol, &Bs[chunk * 512]);    \
    }                                                                          \
    __syncthreads();                                                           \
    bf16x8 af[4], bfr[4];                                                      \
    _Pragma("unroll")                                                          \
    for (int f = 0; f < 4; ++f) {                                              \
      af[f]  = *(const bf16x8*)&As[(wr * 64 + f * 16 + lr) * 32 + lg * 8];     \
      bfr[f] = *(const bf16x8*)&Bs[(wc * 64 + f * 16 + lr) * 32 + lg * 8];     \
    }                                                                          \
    _Pragma("unroll")                                                          \
    for (int fi = 0; fi < 4; ++fi)                                             \
      _Pragma("unroll")                                                        \
      for (int fj = 0; fj < 4; ++fj)                                           \
        acc[fi][fj] = __builtin_amdgcn_mfma_f32_16x16x32_bf16(                 \
            af[fi], bfr[fj], acc[fi][fj], 0, 0, 0);                            \
  }

// GEMM1 (fused QKV projection): qkv = xb @ waT^T; epilogue scatters bf16 into
// q[B][H][T][D], k[B][H][T][D], v^T[B][H][D][T].
__global__ __launch_bounds__(256) void gemm_qkv_kernel(
    const unsigned short* __restrict__ A, const unsigned short* __restrict__ Bt,
    unsigned short* __restrict__ qh, unsigned short* __restrict__ kh,
    unsigned short* __restrict__ vtg) {
  const int K = Cc;
  GEMM_CORE_PROLOGUE()

  // Epilogue: n in one region per block (768 % 128 == 0).
  const int region = bcol / Cc;        // 0=q, 1=k, 2=v
  const int nb = bcol - region * Cc;
#pragma unroll
  for (int fi = 0; fi < 4; ++fi) {
    const int m0 = brow + wr * 64 + fi * 16 + lg * 4;
    const int b_ = m0 >> 10, t0 = m0 & 1023;
#pragma unroll
    for (int fj = 0; fj < 4; ++fj) {
      const int n = nb + wc * 64 + fj * 16 + lr;
      const int h_ = n >> 6, d_ = n & 63;
      if (region < 2) {
        unsigned short* dst = (region == 0 ? qh : kh) +
            (((size_t)(b_ * Hh + h_)) * Tt + t0) * Dd + d_;
#pragma unroll
        for (int r = 0; r < 4; ++r) dst[(size_t)r * Dd] = f2bf(acc[fi][fj][r]);
      } else {
        ushort4 w;
        w.x = f2bf(acc[fi][fj][0]);
        w.y = f2bf(acc[fi][fj][1]);
        w.z = f2bf(acc[fi][fj][2]);
        w.w = f2bf(acc[fi][fj][3]);
        *(ushort4*)(vtg + (((size_t)(b_ * Hh + h_)) * Dd + d_) * Tt + t0) = w;
      }
    }
  }
}

// GEMM2: C[M][N] fp32 = A[M][K](bf16) * Bt[N][K]^T(bf16)
__global__ __launch_bounds__(256) void gemm_bt_kernel(
    const unsigned short* __restrict__ A, const unsigned short* __restrict__ Bt,
    float* __restrict__ Cm, int M, int N, int K) {
  GEMM_CORE_PROLOGUE()

#pragma unroll
  for (int fi = 0; fi < 4; ++fi) {
    const size_t rbase = (size_t)(brow + wr * 64 + fi * 16 + lg * 4);
#pragma unroll
    for (int fj = 0; fj < 4; ++fj) {
      const int cbase = bcol + wc * 64 + fj * 16 + lr;
#pragma unroll
      for (int r = 0; r < 4; ++r)
        Cm[(rbase + r) * N + cbase] = acc[fi][fj][r];
    }
  }
}

// ---------------------------------------------------------------------------
// MFMA flash attention v4: QBLK=64 (4 waves x 16 q-rows), KVBLK=128.
// Each block processes qtile PAIR (15-pair, pair): uniform 9 K-tile steps
// per block -> no scheduling tail. Grid (96 bh, 8 pairs): linear id =
// bh + 96*pair, 96 % 8 == 0 -> all pair-blocks of one (b,h) on the SAME XCD
// -> K/V L2-resident. T5 setprio around MFMA clusters. T14 staging split.
// Diagonal tile: wave-uniform jk-limit = (qt&1)*4 + wave.
// ---------------------------------------------------------------------------
__global__ __launch_bounds__(256, 4) void attn_mfma4_kernel(
    const unsigned short* __restrict__ qh, const unsigned short* __restrict__ kh,
    const unsigned short* __restrict__ vtg, unsigned short* __restrict__ y) {
  const int bh = blockIdx.x;          // 0..95 = b*Hh + h
  const int pair = blockIdx.y;        // 0..7
  const int b = bh / Hh, h = bh % Hh;

  const int tid = threadIdx.x;
  const int wave = tid >> 6, lane = tid & 63;   // wave 0..3
  const int lr = lane & 15;
  const int lg = lane >> 4;

  __shared__ unsigned short Ks[128][72];   // [tk][d0..63 +pad]
  __shared__ unsigned short Vt[64][136];   // [d][tk0..127 +pad]

  const size_t head = (size_t)bh * (Tt * Dd);
  constexpr float kS = 0.125f * 1.4426950408889634f;  // 1/sqrt(D) * log2(e)

#pragma unroll
  for (int half = 0; half < 2; ++half) {
    const int qt = (half == 0) ? (15 - pair) : pair;   // big qtile first
    const int qbase = qt * 64;
    const int qrow = qbase + wave * 16 + lr;           // per-lane q row
    const int lastT = qt >> 1;
    const int relo = (qt & 1) * 4;                     // jk offset of triangle

    // Q fragments (registers)
    const unsigned short* qp = qh + head + (size_t)qrow * Dd;
    const bf16x8 qf0 = *(const bf16x8*)(qp + lg * 8);
    const bf16x8 qf1 = *(const bf16x8*)(qp + 32 + lg * 8);

    f32x4 o[4] = {};          // O^T: d = jd*16 + lg*4 + r, q = lr
    float m_run = -INFINITY;
    float l_run = 0.0f;

    // ---- stage tile 0 of this half ----
    __syncthreads();   // all waves done with previous half's LDS
    {
      const unsigned short* kp = kh + head;
      const unsigned short* vp = vtg + head;
#pragma unroll
      for (int it = 0; it < 4; ++it) {
        const int s = tid + 256 * it;        // 0..1023
        *(u16x8*)&Ks[s >> 3][(s & 7) * 8] =
            *(const u16x8*)(kp + (size_t)(s >> 3) * Dd + (s & 7) * 8);
        *(u16x8*)&Vt[s >> 4][(s & 15) * 8] =
            *(const u16x8*)(vp + (size_t)(s >> 4) * Tt + (s & 15) * 8);
      }
    }
    __syncthreads();

    for (int kt2 = 0; kt2 <= lastT; ++kt2) {
      const int kbase = kt2 * 128;
      const bool diagt = (kt2 == lastT);
      const int jklim = diagt ? (relo + wave) : 7;   // inclusive, wave-uniform

      // ---- S^T = K Q^T ----
      f32x4 sT[8];
      __builtin_amdgcn_s_setprio(1);
#pragma unroll
      for (int jk = 0; jk < 8; ++jk) {
        if (jk <= jklim) {
          const bf16x8 kf0 = *(const bf16x8*)&Ks[jk * 16 + lr][lg * 8];
          const bf16x8 kf1 = *(const bf16x8*)&Ks[jk * 16 + lr][32 + lg * 8];
          f32x4 t = {};
          t = __builtin_amdgcn_mfma_f32_16x16x32_bf16(kf0, qf0, t, 0, 0, 0);
          t = __builtin_amdgcn_mfma_f32_16x16x32_bf16(kf1, qf1, t, 0, 0, 0);
          sT[jk] = t;
        }
      }
      __builtin_amdgcn_s_setprio(0);

      // ---- T14: next tile's global loads into regs ----
      u16x8 gk[4], gv[4];
      const bool havenext = (kt2 < lastT);
      if (havenext) {
        const unsigned short* kp = kh + head + (size_t)(kbase + 128) * Dd;
        const unsigned short* vp = vtg + head + (kbase + 128);
#pragma unroll
        for (int it = 0; it < 4; ++it) {
          const int s = tid + 256 * it;
          gk[it] = *(const u16x8*)(kp + (size_t)(s >> 3) * Dd + (s & 7) * 8);
          gv[it] = *(const u16x8*)(vp + (size_t)(s >> 4) * Tt + (s & 15) * 8);
        }
      }

      // ---- causal mask (triangle block jk == relo+wave, diag tile only) ----
      if (diagt) {
#pragma unroll
        for (int r = 0; r < 4; ++r) {
          const int k = kbase + (relo + wave) * 16 + lg * 4 + r;
          if (k > qrow) sT[relo + wave][r] = -INFINITY;
        }
      }

      // ---- online softmax: in-register + 2 shfls ----
      float mx = -INFINITY;
#pragma unroll
      for (int jk = 0; jk < 8; ++jk) {
        if (jk <= jklim) {
          const float a0 = fmaxf(sT[jk][0], sT[jk][1]);
          const float a1 = fmaxf(sT[jk][2], sT[jk][3]);
          mx = fmaxf(mx, fmaxf(a0, a1));
        }
      }
      mx = fmaxf(mx, __shfl_xor(mx, 16));
      mx = fmaxf(mx, __shfl_xor(mx, 32));
      const float mnew = fmaxf(m_run, mx);
      const float mkS = mnew * kS;

      f32x4 lsv = {};
      bf16x4 pa[8];
#pragma unroll
      for (int jk = 0; jk < 8; ++jk) {
        if (jk <= jklim) {
          f32x4 p;
#pragma unroll
          for (int r = 0; r < 4; ++r)
            p[r] = fast_exp2(__builtin_fmaf(sT[jk][r], kS, -mkS));
          lsv += p;
          pa[jk][0] = f2bf_hw(p[0]); pa[jk][1] = f2bf_hw(p[1]);
          pa[jk][2] = f2bf_hw(p[2]); pa[jk][3] = f2bf_hw(p[3]);
        }
      }
      float ls = (lsv[0] + lsv[1]) + (lsv[2] + lsv[3]);
      ls += __shfl_xor(ls, 16);
      ls += __shfl_xor(ls, 32);

      const float alpha = fast_exp2((m_run - mnew) * kS);   // 0 on first tile
      l_run = l_run * alpha + ls;
      m_run = mnew;
#pragma unroll
      for (int jd = 0; jd < 4; ++jd)
#pragma unroll
        for (int r = 0; r < 4; ++r) o[jd][r] *= alpha;

      // ---- O^T += V^T P^T ----
      __builtin_amdgcn_s_setprio(1);
#pragma unroll
      for (int jk = 0; jk < 8; ++jk) {
        if (jk <= jklim) {
#pragma unroll
          for (int jd = 0; jd < 4; ++jd) {
            const bf16x4 vtf = *(const bf16x4*)&Vt[jd * 16 + lr][jk * 16 + lg * 4];
            o[jd] = mfma16_bf16(vtf, pa[jk], o[jd]);
          }
        }
      }
      __builtin_amdgcn_s_setprio(0);

      // ---- write next tile to LDS ----
      __syncthreads();
      if (havenext) {
#pragma unroll
        for (int it = 0; it < 4; ++it) {
          const int s = tid + 256 * it;
          *(u16x8*)&Ks[s >> 3][(s & 7) * 8] = gk[it];
          *(u16x8*)&Vt[s >> 4][(s & 15) * 8] = gv[it];
        }
        __syncthreads();
      }
    }

    // ---- epilogue for this half ----
    const float inv = 1.0f / l_run;
    unsigned short* yp = y + (size_t)(b * Tt + qrow) * Cc + h * Dd;
#pragma unroll
    for (int jd = 0; jd < 4; ++jd) {
      ushort4 w;
      w.x = (unsigned short)f2bf_hw(o[jd][0] * inv);
      w.y = (unsigned short)f2bf_hw(o[jd][1] * inv);
      w.z = (unsigned short)f2bf_hw(o[jd][2] * inv);
      w.w = (unsigned short)f2bf_hw(o[jd][3] * inv);
      *(ushort4*)(yp + jd * 16 + lg * 4) = w;
    }
  }
}

// ---------------------------------------------------------------------------
extern "C" void kernel_launch(void* const* d_in, const int* in_sizes, int n_in,
                              void* d_out, int out_size, void* d_ws, size_t ws_size,
                              hipStream_t stream) {
  const float* x = (const float*)d_in[0];        // [8,1024,768]
  const float* w_attn = (const float*)d_in[1];   // [768, 2304]
  const float* w_proj = (const float*)d_in[2];   // [768, 768]
  float* out = (float*)d_out;                    // [8,1024,768] fp32

  const size_t headTD = (size_t)Bz * Hh * Tt * Dd;   // 6.29M elems
  unsigned short* xb   = (unsigned short*)d_ws;      // [8192][768] bf16
  unsigned short* qh   = xb + (size_t)BT * Cc;       // [B][H][T][D]
  unsigned short* kh   = qh + headTD;                // [B][H][T][D]
  unsigned short* vtg  = kh + headTD;                // [B][H][D][T]
  unsigned short* yatt = vtg + headTD;               // [BT][Cc]
  unsigned short* waT  = yatt + (size_t)BT * Cc;     // [2304][768]
  unsigned short* wpT  = waT + (size_t)C3 * Cc;      // [768][768]

  // 0) casts (xcast REQUIRED: global_load_lds staging cannot cast)
  xcast_kernel<<<(BT * Cc) / (256 * 8), 256, 0, stream>>>(x, xb);
  tcast_kernel<<<dim3(C3 / 32, Cc / 32), dim3(32, 8), 0, stream>>>(w_attn, waT, Cc, C3);
  tcast_kernel<<<dim3(Cc / 32, Cc / 32), dim3(32, 8), 0, stream>>>(w_proj, wpT, Cc, Cc);

  // 1) fused QKV projection with layout-shuffled bf16 outputs
  gemm_qkv_kernel<<<dim3(C3 / 128, BT / 128), 256, 0, stream>>>(xb, waT, qh, kh, vtg);

  // 2) MFMA flash attention v4 (paired qtiles, XCD-local K/V)
  attn_mfma4_kernel<<<dim3(Bz * Hh, 8), 256, 0, stream>>>(qh, kh, vtg, yatt);

  // 3) out = yatt @ w_proj
  gemm_bt_kernel<<<dim3(Cc / 128, BT / 128), 256, 0, stream>>>(
      yatt, wpT, out, BT, Cc, Cc);
}

// Round 10
// 207.800 us; speedup vs baseline: 1.1401x; 1.1401x over previous
//
#include <hip/hip_runtime.h>
#include <hip/hip_bf16.h>
#include <math.h>

// Problem constants (GPT-2 small causal self-attention)
constexpr int Bz = 8;      // batch
constexpr int Tt = 1024;   // seq len
constexpr int Cc = 768;    // n_embd
constexpr int Hh = 12;     // heads
constexpr int Dd = 64;     // head dim
constexpr int BT = Bz * Tt;        // 8192 rows
constexpr int C3 = 3 * Cc;         // 2304

using bf16x8 = __attribute__((ext_vector_type(8))) short;
using bf16x4 = __attribute__((ext_vector_type(4))) short;
using u16x8  = __attribute__((ext_vector_type(8))) unsigned short;
using f32x4  = __attribute__((ext_vector_type(4))) float;

__device__ __forceinline__ unsigned short f2bf(float f) {   // bit-exact RNE (cold paths)
  unsigned int u = __builtin_bit_cast(unsigned int, f);
  u += 0x7fffu + ((u >> 16) & 1u);
  return (unsigned short)(u >> 16);
}
__device__ __forceinline__ short f2bf_hw(float f) {         // HW cvt (hot path)
  __hip_bfloat16 h = __float2bfloat16(f);
  return __builtin_bit_cast(short, h);
}
__device__ __forceinline__ float fast_exp2(float x) {
#if __has_builtin(__builtin_amdgcn_exp2f)
  return __builtin_amdgcn_exp2f(x);
#else
  return exp2f(x);
#endif
}
__device__ __forceinline__ f32x4 mfma16_bf16(bf16x4 a, bf16x4 b, f32x4 c) {
#if __has_builtin(__builtin_amdgcn_mfma_f32_16x16x16bf16_1k)
  return __builtin_amdgcn_mfma_f32_16x16x16bf16_1k(a, b, c, 0, 0, 0);
#else
  asm volatile("v_mfma_f32_16x16x16_bf16 %0, %1, %2, %0" : "+v"(c) : "v"(a), "v"(b));
  return c;
#endif
}
// async global->LDS, 16B per lane; dest is wave-uniform base + lane*16 (m97/m104)
__device__ __forceinline__ void stage16(const unsigned short* g, unsigned short* l) {
  __builtin_amdgcn_global_load_lds(
      (const __attribute__((address_space(1))) void*)g,
      (__attribute__((address_space(3))) void*)l, 16, 0, 0);
}

// ---------------------------------------------------------------------------
// Unified prep kernel (1 launch instead of 3):
//   blocks [0, 3072):        x fp32 -> xb bf16 (8 elems/thread)
//   blocks [3072, 4800):     w_attn [768][2304] -> waT [2304][768] bf16
//   blocks [4800, 5376):     w_proj [768][768]  -> wpT [768][768]  bf16
// ---------------------------------------------------------------------------
__global__ __launch_bounds__(256) void prep_kernel(
    const float* __restrict__ x, unsigned short* __restrict__ xb,
    const float* __restrict__ w_attn, unsigned short* __restrict__ waT,
    const float* __restrict__ w_proj, unsigned short* __restrict__ wpT) {
  __shared__ float t[32][33];
  const int blk = blockIdx.x;
  const int tid = threadIdx.x;
  if (blk < 3072) {
    const size_t i = ((size_t)blk * 256 + tid) * 8;
    const float4 a = *(const float4*)(x + i);
    const float4 b = *(const float4*)(x + i + 4);
    u16x8 w;
    w[0] = f2bf(a.x); w[1] = f2bf(a.y); w[2] = f2bf(a.z); w[3] = f2bf(a.w);
    w[4] = f2bf(b.x); w[5] = f2bf(b.y); w[6] = f2bf(b.z); w[7] = f2bf(b.w);
    *(u16x8*)(xb + i) = w;
  } else {
    const float* in;
    unsigned short* out;
    int K, N, bx, by;
    if (blk < 3072 + 1728) {
      const int b2 = blk - 3072;
      in = w_attn; out = waT; K = Cc; N = C3;
      bx = b2 % 72; by = b2 / 72;
    } else {
      const int b3 = blk - (3072 + 1728);
      in = w_proj; out = wpT; K = Cc; N = Cc;
      bx = b3 % 24; by = b3 / 24;
    }
    const int tx = tid & 31, ty = tid >> 5;
    const int kb = by * 32, nb = bx * 32;
#pragma unroll
    for (int i = 0; i < 4; ++i)
      t[ty + 8 * i][tx] = in[(size_t)(kb + ty + 8 * i) * N + nb + tx];
    __syncthreads();
#pragma unroll
    for (int i = 0; i < 4; ++i)
      out[(size_t)(nb + ty + 8 * i) * K + kb + tx] = f2bf(t[tx][ty + 8 * i]);
  }
}

// ---------------------------------------------------------------------------
// m97-structure MFMA GEMM core (B^T input, both bf16):
// 128x128 tile, BK=32, linear LDS [128][32], global_load_lds width 16.
// Wave w stages A/B chunks (w*2, w*2+1); chunk = 16 rows = 1KB.
// T1 bijective XCD swizzle (m204): nwg % 8 == 0 for both GEMMs (1152, 384);
// chunked remap gives each XCD contiguous row-panels -> A-panel + B L2 reuse.
// ---------------------------------------------------------------------------
#define GEMM_CORE_PROLOGUE()                                                   \
  __shared__ unsigned short As[128 * 32];                                      \
  __shared__ unsigned short Bs[128 * 32];                                      \
  const int tid = threadIdx.x;                                                 \
  const int wave = tid >> 6, lane = tid & 63;                                  \
  const int wr = wave >> 1, wc = wave & 1;                                     \
  const int lr = lane & 15;                                                    \
  const int lg = lane >> 4;                                                    \
  const int lrow = lane >> 2;                                                  \
  const int lcol = (lane & 3) * 8;                                             \
  const int nx = gridDim.x;                                                    \
  const int lin = blockIdx.x + nx * blockIdx.y;                                \
  const int cpx = (nx * gridDim.y) >> 3;                                       \
  const int swz = (lin & 7) * cpx + (lin >> 3);                                \
  const int brow = (swz / nx) * 128, bcol = (swz % nx) * 128;                  \
  f32x4 acc[4][4] = {};                                                        \
  for (int kt = 0; kt < K / 32; ++kt) {                                        \
    const int k0 = kt * 32;                                                    \
    __syncthreads();                                                           \
    _Pragma("unroll")                                                          \
    for (int i = 0; i < 2; ++i) {                                              \
      const int chunk = wave * 2 + i;                                          \
      const int row = chunk * 16 + lrow;                                       \
      stage16(A + (size_t)(brow + row) * K + k0 + lcol, &As[chunk * 512]);     \
      stage16(Bt + (size_t)(bcol + row) * K + k0 + lcol, &Bs[chunk * 512]);    \
    }                                                                          \
    __syncthreads();                                                           \
    bf16x8 af[4], bfr[4];                                                      \
    _Pragma("unroll")                                                          \
    for (int f = 0; f < 4; ++f) {                                              \
      af[f]  = *(const bf16x8*)&As[(wr * 64 + f * 16 + lr) * 32 + lg * 8];     \
      bfr[f] = *(const bf16x8*)&Bs[(wc * 64 + f * 16 + lr) * 32 + lg * 8];     \
    }                                                                          \
    _Pragma("unroll")                                                          \
    for (int fi = 0; fi < 4; ++fi)                                             \
      _Pragma("unroll")                                                        \
      for (int fj = 0; fj < 4; ++fj)                                           \
        acc[fi][fj] = __builtin_amdgcn_mfma_f32_16x16x32_bf16(                 \
            af[fi], bfr[fj], acc[fi][fj], 0, 0, 0);                            \
  }

// GEMM1 (fused QKV projection): qkv = xb @ waT^T; epilogue scatters bf16 into
// q[B][H][T][D], k[B][H][T][D], v^T[B][H][D][T].
__global__ __launch_bounds__(256) void gemm_qkv_kernel(
    const unsigned short* __restrict__ A, const unsigned short* __restrict__ Bt,
    unsigned short* __restrict__ qh, unsigned short* __restrict__ kh,
    unsigned short* __restrict__ vtg) {
  const int K = Cc;
  GEMM_CORE_PROLOGUE()

  // Epilogue: n in one region per block (768 % 128 == 0).
  const int region = bcol / Cc;        // 0=q, 1=k, 2=v
  const int nb = bcol - region * Cc;
#pragma unroll
  for (int fi = 0; fi < 4; ++fi) {
    const int m0 = brow + wr * 64 + fi * 16 + lg * 4;
    const int b_ = m0 >> 10, t0 = m0 & 1023;
#pragma unroll
    for (int fj = 0; fj < 4; ++fj) {
      const int n = nb + wc * 64 + fj * 16 + lr;
      const int h_ = n >> 6, d_ = n & 63;
      if (region < 2) {
        unsigned short* dst = (region == 0 ? qh : kh) +
            (((size_t)(b_ * Hh + h_)) * Tt + t0) * Dd + d_;
#pragma unroll
        for (int r = 0; r < 4; ++r) dst[(size_t)r * Dd] = f2bf(acc[fi][fj][r]);
      } else {
        ushort4 w;
        w.x = f2bf(acc[fi][fj][0]);
        w.y = f2bf(acc[fi][fj][1]);
        w.z = f2bf(acc[fi][fj][2]);
        w.w = f2bf(acc[fi][fj][3]);
        *(ushort4*)(vtg + (((size_t)(b_ * Hh + h_)) * Dd + d_) * Tt + t0) = w;
      }
    }
  }
}

// GEMM2: C[M][N] fp32 = A[M][K](bf16) * Bt[N][K]^T(bf16)
__global__ __launch_bounds__(256) void gemm_bt_kernel(
    const unsigned short* __restrict__ A, const unsigned short* __restrict__ Bt,
    float* __restrict__ Cm, int M, int N, int K) {
  GEMM_CORE_PROLOGUE()

#pragma unroll
  for (int fi = 0; fi < 4; ++fi) {
    const size_t rbase = (size_t)(brow + wr * 64 + fi * 16 + lg * 4);
#pragma unroll
    for (int fj = 0; fj < 4; ++fj) {
      const int cbase = bcol + wc * 64 + fj * 16 + lr;
#pragma unroll
      for (int r = 0; r < 4; ++r)
        Cm[(rbase + r) * N + cbase] = acc[fi][fj][r];
    }
  }
}

// ---------------------------------------------------------------------------
// MFMA flash attention v3 (round-8 known-good, reverted from v4 which spilled:
// WRITE_SIZE 200MB scratch thrash at QBLK=64+gk[4]/gv[4]).
// Swapped QK^T, in-register softmax, PV via 16x16x16. QBLK=128 (8 waves x 16
// q-rows), KVBLK=128. Big-first grid. Ks[128][72], Vt[64][136].
// T14: next-tile global loads into regs during compute, LDS-write after barrier.
// ---------------------------------------------------------------------------
__global__ __launch_bounds__(512, 4) void attn_mfma3_kernel(
    const unsigned short* __restrict__ qh, const unsigned short* __restrict__ kh,
    const unsigned short* __restrict__ vtg, unsigned short* __restrict__ y) {
  const int qtile = (Tt / 128 - 1) - blockIdx.x;   // big-first
  const int h = blockIdx.y;
  const int b = blockIdx.z;
  const int qbase = qtile * 128;

  const int tid = threadIdx.x;
  const int wave = tid >> 6, lane = tid & 63;
  const int lr = lane & 15;
  const int lg = lane >> 4;

  __shared__ unsigned short Ks[128][72];   // [tk][d0..63 +pad]
  __shared__ unsigned short Vt[64][136];   // [d][tk0..127 +pad]

  const size_t head = ((size_t)(b * Hh + h)) * (Tt * Dd);
  const int qrow = qbase + wave * 16 + lr;       // per-lane q row

  bf16x8 qf0, qf1;
  {
    const unsigned short* qp = qh + head + (size_t)qrow * Dd;
    qf0 = *(const bf16x8*)(qp + lg * 8);
    qf1 = *(const bf16x8*)(qp + 32 + lg * 8);
  }

  f32x4 o[4] = {};          // O^T: d = jd*16 + lg*4 + r, q = lr
  float m_run = -INFINITY;
  float l_run = 0.0f;

  constexpr float kS = 0.125f * 1.4426950408889634f;  // 1/sqrt(D) * log2(e)
  const int lastT = qtile;

  // ---- prologue: stage tile 0 ----
  {
    const unsigned short* kp = kh + head;
    const unsigned short* vp = vtg + head;
#pragma unroll
    for (int it = 0; it < 2; ++it) {
      const int s = tid + 512 * it;        // 0..1023
      *(u16x8*)&Ks[s >> 3][(s & 7) * 8] =
          *(const u16x8*)(kp + (size_t)(s >> 3) * Dd + (s & 7) * 8);
      *(u16x8*)&Vt[s >> 4][(s & 15) * 8] =
          *(const u16x8*)(vp + (size_t)(s >> 4) * Tt + (s & 15) * 8);
    }
  }
  __syncthreads();

  for (int kt2 = 0; kt2 <= lastT; ++kt2) {
    const int kbase = kt2 * 128;
    const bool diagt = (kt2 == lastT);

    // ---- S^T = K Q^T ----
    f32x4 sT[8];
#pragma unroll
    for (int jk = 0; jk < 8; ++jk) {
      if (!diagt || jk <= wave) {
        const bf16x8 kf0 = *(const bf16x8*)&Ks[jk * 16 + lr][lg * 8];
        const bf16x8 kf1 = *(const bf16x8*)&Ks[jk * 16 + lr][32 + lg * 8];
        f32x4 t = {};
        t = __builtin_amdgcn_mfma_f32_16x16x32_bf16(kf0, qf0, t, 0, 0, 0);
        t = __builtin_amdgcn_mfma_f32_16x16x32_bf16(kf1, qf1, t, 0, 0, 0);
        sT[jk] = t;
      }
    }

    // ---- T14: next tile's global loads into regs ----
    u16x8 gk[2], gv[2];
    const bool havenext = (kt2 < lastT);
    if (havenext) {
      const unsigned short* kp = kh + head + (size_t)(kbase + 128) * Dd;
      const unsigned short* vp = vtg + head + (kbase + 128);
#pragma unroll
      for (int it = 0; it < 2; ++it) {
        const int s = tid + 512 * it;
        gk[it] = *(const u16x8*)(kp + (size_t)(s >> 3) * Dd + (s & 7) * 8);
        gv[it] = *(const u16x8*)(vp + (size_t)(s >> 4) * Tt + (s & 15) * 8);
      }
    }

    // ---- causal mask (triangle block jk==wave of diagonal tile) ----
    if (diagt) {
#pragma unroll
      for (int r = 0; r < 4; ++r) {
        const int k = kbase + wave * 16 + lg * 4 + r;
        if (k > qrow) sT[wave][r] = -INFINITY;
      }
    }

    // ---- online softmax: in-register + 2 shfls ----
    float mx = -INFINITY;
#pragma unroll
    for (int jk = 0; jk < 8; ++jk) {
      if (!diagt || jk <= wave) {
        const float a0 = fmaxf(sT[jk][0], sT[jk][1]);
        const float a1 = fmaxf(sT[jk][2], sT[jk][3]);
        mx = fmaxf(mx, fmaxf(a0, a1));
      }
    }
    mx = fmaxf(mx, __shfl_xor(mx, 16));
    mx = fmaxf(mx, __shfl_xor(mx, 32));
    const float mnew = fmaxf(m_run, mx);
    const float mkS = mnew * kS;

    f32x4 lsv = {};
    bf16x4 pa[8];
#pragma unroll
    for (int jk = 0; jk < 8; ++jk) {
      if (!diagt || jk <= wave) {
        f32x4 p;
#pragma unroll
        for (int r = 0; r < 4; ++r)
          p[r] = fast_exp2(__builtin_fmaf(sT[jk][r], kS, -mkS));
        lsv += p;
        pa[jk][0] = f2bf_hw(p[0]); pa[jk][1] = f2bf_hw(p[1]);
        pa[jk][2] = f2bf_hw(p[2]); pa[jk][3] = f2bf_hw(p[3]);
      }
    }
    float ls = (lsv[0] + lsv[1]) + (lsv[2] + lsv[3]);
    ls += __shfl_xor(ls, 16);
    ls += __shfl_xor(ls, 32);

    const float alpha = fast_exp2((m_run - mnew) * kS);   // 0 on first tile
    l_run = l_run * alpha + ls;
    m_run = mnew;
#pragma unroll
    for (int jd = 0; jd < 4; ++jd)
#pragma unroll
      for (int r = 0; r < 4; ++r) o[jd][r] *= alpha;

    // ---- O^T += V^T P^T ----
#pragma unroll
    for (int jk = 0; jk < 8; ++jk) {
      if (!diagt || jk <= wave) {
#pragma unroll
        for (int jd = 0; jd < 4; ++jd) {
          const bf16x4 vtf = *(const bf16x4*)&Vt[jd * 16 + lr][jk * 16 + lg * 4];
          o[jd] = mfma16_bf16(vtf, pa[jk], o[jd]);
        }
      }
    }

    // ---- write next tile to LDS ----
    __syncthreads();
    if (havenext) {
#pragma unroll
      for (int it = 0; it < 2; ++it) {
        const int s = tid + 512 * it;
        *(u16x8*)&Ks[s >> 3][(s & 7) * 8] = gk[it];
        *(u16x8*)&Vt[s >> 4][(s & 15) * 8] = gv[it];
      }
      __syncthreads();
    }
  }

  // ---- epilogue ----
  const float inv = 1.0f / l_run;
  unsigned short* yp = y + (size_t)(b * Tt + qrow) * Cc + h * Dd;
#pragma unroll
  for (int jd = 0; jd < 4; ++jd) {
    ushort4 w;
    w.x = (unsigned short)f2bf_hw(o[jd][0] * inv);
    w.y = (unsigned short)f2bf_hw(o[jd][1] * inv);
    w.z = (unsigned short)f2bf_hw(o[jd][2] * inv);
    w.w = (unsigned short)f2bf_hw(o[jd][3] * inv);
    *(ushort4*)(yp + jd * 16 + lg * 4) = w;
  }
}

// ---------------------------------------------------------------------------
extern "C" void kernel_launch(void* const* d_in, const int* in_sizes, int n_in,
                              void* d_out, int out_size, void* d_ws, size_t ws_size,
                              hipStream_t stream) {
  const float* x = (const float*)d_in[0];        // [8,1024,768]
  const float* w_attn = (const float*)d_in[1];   // [768, 2304]
  const float* w_proj = (const float*)d_in[2];   // [768, 768]
  float* out = (float*)d_out;                    // [8,1024,768] fp32

  const size_t headTD = (size_t)Bz * Hh * Tt * Dd;   // 6.29M elems
  unsigned short* xb   = (unsigned short*)d_ws;      // [8192][768] bf16
  unsigned short* qh   = xb + (size_t)BT * Cc;       // [B][H][T][D]
  unsigned short* kh   = qh + headTD;                // [B][H][T][D]
  unsigned short* vtg  = kh + headTD;                // [B][H][D][T]
  unsigned short* yatt = vtg + headTD;               // [BT][Cc]
  unsigned short* waT  = yatt + (size_t)BT * Cc;     // [2304][768]
  unsigned short* wpT  = waT + (size_t)C3 * Cc;      // [768][768]

  // 0) unified prep: xb + waT + wpT in one launch
  prep_kernel<<<3072 + 1728 + 576, 256, 0, stream>>>(
      x, xb, w_attn, waT, w_proj, wpT);

  // 1) fused QKV projection with layout-shuffled bf16 outputs (T1 swizzled)
  gemm_qkv_kernel<<<dim3(C3 / 128, BT / 128), 256, 0, stream>>>(xb, waT, qh, kh, vtg);

  // 2) MFMA flash attention v3 (round-8 revert)
  attn_mfma3_kernel<<<dim3(Tt / 128, Hh, Bz), 512, 0, stream>>>(qh, kh, vtg, yatt);

  // 3) out = yatt @ w_proj (T1 swizzled)
  gemm_bt_kernel<<<dim3(Cc / 128, BT / 128), 256, 0, stream>>>(
      yatt, wpT, out, BT, Cc, Cc);
}